// Round 4
// baseline (450.634 us; speedup 1.0000x reference)
//
#include <hip/hip_runtime.h>
#include <math.h>

#define NB 8
#define NT 2048
#define ND 256
#define NR (NB*NT)   // 16384 rows

typedef _Float16 f16x8 __attribute__((ext_vector_type(8)));
typedef _Float16 f16x4 __attribute__((ext_vector_type(4)));
typedef float f32x4 __attribute__((ext_vector_type(4)));

// log2(e)/16 : folds 1/sqrt(256) and exp->exp2 into q
#define QSCALE 0.09016844005556021f
// fixed softmax max (log2 domain). |s| <= 23 hard bound (LN norms = 16) -> p <= 2^15 fits f16.
#define MFIX 8.0f

__device__ __forceinline__ float sigm_(float x) { return 1.0f / (1.0f + __expf(-x)); }
__device__ __forceinline__ float tanh_(float x) { return 1.0f - 2.0f / (__expf(2.0f*x) + 1.0f); }

// ---------------------------------------------------------------------------
// prep2 (one launch, 88 blocks x 256):
//  bid 0..15  : WcqT[n][k] = f16( sum_m Wql[k][m]*Wq[m][n] )   (64x64 tiles)
//  bid 16..79 : WT[z][n][k] = f16(W_z[k][n]), z=1..4 for {Wk,Wv,Ws,Wt} top half
//  bid 80..87 : per-batch fused biases + vmean zero
// ---------------------------------------------------------------------------
__global__ __launch_bounds__(256) void prep2(
    const float* __restrict__ Wql, const float* __restrict__ bql,
    const float* __restrict__ Wq,  const float* __restrict__ bq,
    const float* __restrict__ Wk,  const float* __restrict__ bk,
    const float* __restrict__ Wv,  const float* __restrict__ bv,
    const float* __restrict__ Ws,  const float* __restrict__ Wt,
    const float* __restrict__ aux, _Float16* __restrict__ WT,
    float* __restrict__ biasq, float* __restrict__ biask,
    float* __restrict__ biasv, float* __restrict__ vmean)
{
  __shared__ float LA[64*68];
  __shared__ float LB[64*68];
  const int bid = blockIdx.x;
  const int tid = threadIdx.x;

  if (bid < 16) {
    // ---- WcqT tile (GEMM + transpose + f16) ----
    const int k0 = (bid & 3) * 64, n0 = (bid >> 2) * 64;
    const int c4 = tid & 15, rr = tid >> 4;
    const int tn = tid & 15, tk = tid >> 4;
    float acc[4][4];
    #pragma unroll
    for (int i = 0; i < 4; ++i)
      #pragma unroll
      for (int j = 0; j < 4; ++j) acc[i][j] = 0.f;

    for (int mc = 0; mc < 4; ++mc) {
      const int m0 = mc * 64;
      #pragma unroll
      for (int i = 0; i < 4; ++i) {
        const int row = rr + 16*i;
        *(float4*)(LA + row*68 + c4*4) =
            *(const float4*)(Wql + (size_t)(k0 + row)*256 + m0 + c4*4);
        *(float4*)(LB + row*68 + c4*4) =
            *(const float4*)(Wq + (size_t)(m0 + row)*256 + n0 + c4*4);
      }
      __syncthreads();
      for (int m = 0; m < 64; ++m) {
        const float4 b4 = *(const float4*)(LB + m*68 + tn*4);
        #pragma unroll
        for (int i = 0; i < 4; ++i) {
          const float a = LA[(tk*4 + i)*68 + m];
          acc[i][0] = fmaf(a, b4.x, acc[i][0]);
          acc[i][1] = fmaf(a, b4.y, acc[i][1]);
          acc[i][2] = fmaf(a, b4.z, acc[i][2]);
          acc[i][3] = fmaf(a, b4.w, acc[i][3]);
        }
      }
      __syncthreads();
    }
    #pragma unroll
    for (int j = 0; j < 4; ++j) {
      f16x4 o;
      #pragma unroll
      for (int i = 0; i < 4; ++i) o[i] = (_Float16)acc[i][j];
      *(f16x4*)(WT + (size_t)(n0 + tn*4 + j)*256 + k0 + tk*4) = o;
    }
  } else if (bid < 80) {
    // ---- simple transpose+f16 of W_z top 256 rows ----
    const int zz = (bid - 16) >> 4;
    const int tile = (bid - 16) & 15;
    const int k0 = (tile & 3)*64, n0 = (tile >> 2)*64;
    const float* src = (zz==0) ? Wk : (zz==1) ? Wv : (zz==2) ? Ws : Wt;
    _Float16* dst = WT + (size_t)(zz + 1)*65536;
    const int c4 = tid & 15, rr = tid >> 4;
    #pragma unroll
    for (int i = 0; i < 4; ++i) {
      const int row = rr + 16*i;
      *(float4*)(LA + row*68 + c4*4) =
          *(const float4*)(src + (size_t)(k0 + row)*256 + n0 + c4*4);
    }
    __syncthreads();
    const int nl = tid >> 2, part = tid & 3;
    f16x8 lo, hi;
    #pragma unroll
    for (int j = 0; j < 8; ++j) lo[j] = (_Float16)LA[(part*16 + j)*68 + nl];
    #pragma unroll
    for (int j = 0; j < 8; ++j) hi[j] = (_Float16)LA[(part*16 + 8 + j)*68 + nl];
    _Float16* op = dst + (size_t)(n0 + nl)*256 + k0 + part*16;
    *(f16x8*)(op)     = lo;
    *(f16x8*)(op + 8) = hi;
  } else {
    // ---- biases + vmean zero ----
    const int b = bid - 80;
    const int j = tid;
    float accq = bq[j], acck = bk[j], accv = bv[j];
    #pragma unroll 4
    for (int n = 0; n < 256; ++n)
      accq = fmaf(bql[n], Wq[n*256 + j], accq);
    #pragma unroll 4
    for (int d = 0; d < 256; ++d) {
      const float a = aux[b*256 + d];
      accq = fmaf(a, Wq[(256 + d)*256 + j], accq);
      acck = fmaf(a, Wk[(256 + d)*256 + j], acck);
      accv = fmaf(a, Wv[(256 + d)*256 + j], accv);
    }
    biasq[b*256 + j] = accq;
    biask[b*256 + j] = acck;
    biasv[b*256 + j] = accv;
    vmean[b*256 + j] = 0.f;
  }
}

// ---------------------------------------------------------------------------
// gemm_all: all three LN streams in ONE launch (z = bid>>10):
//   z0: q = LN(PReLU(query@WcqT + biasq)) * QSCALE -> qbuf
//   z1: k = LN(PReLU(value@WkT + biask))           -> kbuf
//   z2: v = LN(PReLU(value@WvT + biasv))           -> vln
// 1 wave per block, 16 rows x 256 cols, MFMA f16 16x16x32.
// ---------------------------------------------------------------------------
__global__ __launch_bounds__(64) void gemm_all(
    const float* __restrict__ query, const float* __restrict__ value,
    const _Float16* __restrict__ WT,
    const float* __restrict__ biasq, const float* __restrict__ biask,
    const float* __restrict__ biasv,
    const float* __restrict__ aq, const float* __restrict__ ak,
    const float* __restrict__ av,
    const float* __restrict__ gq, const float* __restrict__ gk,
    const float* __restrict__ gv,
    const float* __restrict__ btq, const float* __restrict__ btk,
    const float* __restrict__ btv,
    _Float16* __restrict__ qbuf, _Float16* __restrict__ kbuf,
    _Float16* __restrict__ vln)
{
  const int bid = blockIdx.x;
  const int z = bid >> 10;
  const int idx = bid & 1023;
  const int lane = threadIdx.x;
  const int fc = lane & 15, sl = lane >> 4;
  const int r0 = idx * 16;
  const int b = idx >> 7;

  const float* in = (z == 0) ? query : value;
  const _Float16* WTz = WT + (size_t)z * 65536;
  const float* bias = (z == 0) ? biasq : (z == 1) ? biask : biasv;
  const float* alp  = (z == 0) ? aq : (z == 1) ? ak : av;
  const float* g    = (z == 0) ? gq : (z == 1) ? gk : gv;
  const float* beta = (z == 0) ? btq : (z == 1) ? btk : btv;
  _Float16* out = (z == 0) ? qbuf : (z == 1) ? kbuf : vln;
  const float scale = (z == 0) ? QSCALE : 1.0f;

  f16x8 a[8];
  const float* ap = in + (size_t)(r0 + fc)*256 + sl*8;
  #pragma unroll
  for (int c = 0; c < 8; ++c) {
    const float4 x0 = *(const float4*)(ap + c*32);
    const float4 x1 = *(const float4*)(ap + c*32 + 4);
    a[c][0] = (_Float16)x0.x; a[c][1] = (_Float16)x0.y;
    a[c][2] = (_Float16)x0.z; a[c][3] = (_Float16)x0.w;
    a[c][4] = (_Float16)x1.x; a[c][5] = (_Float16)x1.y;
    a[c][6] = (_Float16)x1.z; a[c][7] = (_Float16)x1.w;
  }

  f32x4 acc[16];
  #pragma unroll
  for (int n = 0; n < 16; ++n) acc[n] = (f32x4)(0.f);

  #pragma unroll
  for (int c = 0; c < 8; ++c) {
    #pragma unroll
    for (int n = 0; n < 16; ++n) {
      const f16x8 bf = *(const f16x8*)(WTz + (size_t)(n*16 + fc)*256 + c*32 + sl*8);
      acc[n] = __builtin_amdgcn_mfma_f32_16x16x32_f16(a[c], bf, acc[n], 0, 0, 0);
    }
  }

  const float alpha = alp[0];
  float s_[4] = {0.f,0.f,0.f,0.f}, ss[4] = {0.f,0.f,0.f,0.f};
  #pragma unroll
  for (int n = 0; n < 16; ++n) {
    const float bb = bias[b*256 + n*16 + fc];
    #pragma unroll
    for (int r = 0; r < 4; ++r) {
      float x = acc[n][r] + bb;
      x = (x >= 0.f) ? x : alpha*x;
      acc[n][r] = x;
      s_[r] += x; ss[r] += x*x;
    }
  }
  #pragma unroll
  for (int off = 1; off < 16; off <<= 1) {
    #pragma unroll
    for (int r = 0; r < 4; ++r) {
      s_[r] += __shfl_xor(s_[r], off, 16);
      ss[r] += __shfl_xor(ss[r], off, 16);
    }
  }
  float mean[4], rstd[4];
  #pragma unroll
  for (int r = 0; r < 4; ++r) {
    mean[r] = s_[r] * (1.f/256.f);
    const float var = ss[r] * (1.f/256.f) - mean[r]*mean[r];
    rstd[r] = rsqrtf(var + 1e-5f);
  }
  #pragma unroll
  for (int n = 0; n < 16; ++n) {
    const int col = n*16 + fc;
    const float gg = g[col], be = beta[col];
    #pragma unroll
    for (int r = 0; r < 4; ++r) {
      const float o = ((acc[n][r] - mean[r])*rstd[r]*gg + be) * scale;
      out[(size_t)(r0 + sl*4 + r)*256 + col] = (_Float16)o;
    }
  }
}

// ---------------------------------------------------------------------------
// gemm_m1: vgate = sigmoid(vln@Ws + bs) * tanh(vln@Wt + bt) -> Vt f16 [b][d][t]
// + per-block column-sum atomics into vmean (replaces vmeanT kernel).
// ---------------------------------------------------------------------------
__global__ __launch_bounds__(64) void gemm_m1(
    const _Float16* __restrict__ vln, const _Float16* __restrict__ WsT,
    const _Float16* __restrict__ WtT, const float* __restrict__ bs,
    const float* __restrict__ bt, _Float16* __restrict__ Vt,
    float* __restrict__ vmean)
{
  const int lane = threadIdx.x;
  const int fc = lane & 15, sl = lane >> 4;
  const int r0 = blockIdx.x * 16;
  const int b = r0 >> 11, t0 = r0 & 2047;

  f16x8 a[8];
  const _Float16* ap = vln + (size_t)(r0 + fc)*256 + sl*8;
  #pragma unroll
  for (int c = 0; c < 8; ++c) a[c] = *(const f16x8*)(ap + c*32);

  f32x4 aS[16], aT[16];
  #pragma unroll
  for (int n = 0; n < 16; ++n) { aS[n] = (f32x4)(0.f); aT[n] = (f32x4)(0.f); }

  #pragma unroll
  for (int c = 0; c < 8; ++c) {
    #pragma unroll
    for (int n = 0; n < 16; ++n) {
      const f16x8 b1 = *(const f16x8*)(WsT + (size_t)(n*16 + fc)*256 + c*32 + sl*8);
      const f16x8 b2 = *(const f16x8*)(WtT + (size_t)(n*16 + fc)*256 + c*32 + sl*8);
      aS[n] = __builtin_amdgcn_mfma_f32_16x16x32_f16(a[c], b1, aS[n], 0, 0, 0);
      aT[n] = __builtin_amdgcn_mfma_f32_16x16x32_f16(a[c], b2, aT[n], 0, 0, 0);
    }
  }

  #pragma unroll
  for (int n = 0; n < 16; ++n) {
    const int col = n*16 + fc;
    const float b1 = bs[col], b2 = bt[col];
    f16x4 o;
    float s = 0.f;
    #pragma unroll
    for (int r = 0; r < 4; ++r) {
      const float v = sigm_(aS[n][r] + b1) * tanh_(aT[n][r] + b2);
      o[r] = (_Float16)v;
      s += v;
    }
    *(f16x4*)(Vt + (size_t)(b*256 + col)*2048 + t0 + sl*4) = o;
    // column partial sum -> vmean (reduce over sl lanes, one atomic per col)
    s += __shfl_xor(s, 16, 64);
    s += __shfl_xor(s, 32, 64);
    if (sl == 0) atomicAdd(vmean + b*256 + col, s * (1.f/2048.f));
  }
}

// ---------------------------------------------------------------------------
// attn: flash attention, f16 MFMA, fixed-max softmax (log2 domain).
// 1024 blocks x 4 waves. b = bid&7 -> XCD-pinned batch (L2-resident K/V).
// Unit = 16 q-rows; 4 waves split col-tiles round-robin; in-block LDS merge.
// ---------------------------------------------------------------------------
__global__ __launch_bounds__(256) void attn(
    const _Float16* __restrict__ qb, const _Float16* __restrict__ kb,
    const _Float16* __restrict__ Vt, const int* __restrict__ ilen,
    const float* __restrict__ vmean, float* __restrict__ outp)
{
  __shared__ _Float16 Ps[4][512];
  __shared__ float Obuf[2][16*260];
  __shared__ float lbuf[2][16];

  const int bid = blockIdx.x;
  const int b = bid & 7;                     // XCD pin (round-robin dispatch)
  const int j = bid >> 3;
  const int qt = (j & 1) ? (127 - (j >> 1)) : (j >> 1);   // heavy/light pair
  const int r0 = qt << 4;
  const int len = ilen[b];
  const int w = threadIdx.x >> 6, lane = threadIdx.x & 63;
  const int fc = lane & 15, sl = lane >> 4;

  if (r0 >= len) {                           // pad-only unit: vmean rows
    const float4 vmv = ((const float4*)(vmean + b*256))[lane];
    #pragma unroll
    for (int r = 0; r < 4; ++r)
      ((float4*)(outp + (size_t)(b*NT + r0 + w*4 + r)*256))[lane] = vmv;
    return;
  }

  const int nt = (min(r0 + 16, len) + 31) >> 5;

  f16x8 aq_[8];
  {
    const _Float16* qp = qb + (size_t)(b*NT + r0 + fc)*ND + sl*8;
    #pragma unroll
    for (int c = 0; c < 8; ++c) aq_[c] = *(const f16x8*)(qp + c*32);
  }

  f32x4 O[16];
  #pragma unroll
  for (int dc = 0; dc < 16; ++dc) O[dc] = (f32x4)(0.f);
  float l_[4] = {0.f, 0.f, 0.f, 0.f};

  const _Float16* kbase = kb + (size_t)b*NT*ND;
  const _Float16* vbase = Vt + (size_t)b*ND*NT;
  _Float16* psw = &Ps[w][0];

  for (int t = w; t < nt; t += 4) {
    const int j0 = t << 5;
    // ---- batch-load all 16 K frags ----
    f16x8 kk[16];
    const _Float16* kp = kbase + (size_t)(j0 + fc)*ND + sl*8;
    #pragma unroll
    for (int c = 0; c < 8; ++c) {
      kk[c]     = *(const f16x8*)(kp + c*32);
      kk[8 + c] = *(const f16x8*)(kp + (size_t)16*ND + c*32);
    }
    // ---- QK^T: 4 independent MFMA chains ----
    f32x4 S0a = (f32x4)(0.f), S0b = (f32x4)(0.f);
    f32x4 S1a = (f32x4)(0.f), S1b = (f32x4)(0.f);
    #pragma unroll
    for (int c = 0; c < 4; ++c) {
      S0a = __builtin_amdgcn_mfma_f32_16x16x32_f16(aq_[c],   kk[c],    S0a, 0, 0, 0);
      S1a = __builtin_amdgcn_mfma_f32_16x16x32_f16(aq_[c],   kk[8+c],  S1a, 0, 0, 0);
      S0b = __builtin_amdgcn_mfma_f32_16x16x32_f16(aq_[4+c], kk[4+c],  S0b, 0, 0, 0);
      S1b = __builtin_amdgcn_mfma_f32_16x16x32_f16(aq_[4+c], kk[12+c], S1b, 0, 0, 0);
    }
    // ---- batch-issue all 16 V frags (latency hides under softmax) ----
    f16x8 vv[16];
    #pragma unroll
    for (int dc = 0; dc < 16; ++dc)
      vv[dc] = *(const f16x8*)(vbase + (size_t)(dc*16 + fc)*NT + j0 + sl*8);

    // ---- mask + fixed-max exp ----
    const int C0 = j0 + fc, C1 = C0 + 16;
    const int Rb = r0 + sl*4;
    float p0[4], p1[4];
    #pragma unroll
    for (int r = 0; r < 4; ++r) {
      const int R = Rb + r;
      const bool okR = (R < len);
      const float x0 = S0a[r] + S0b[r];
      const float x1 = S1a[r] + S1b[r];
      p0[r] = (okR && (C0 <= R) && (x0 != 0.f)) ? exp2f(x0 - MFIX) : 0.f;
      p1[r] = (okR && (C1 <= R) && (x1 != 0.f)) ? exp2f(x1 - MFIX) : 0.f;
      l_[r] += p0[r] + p1[r];
    }
    // ---- P: C-layout -> f16 A-frag via swizzled per-wave LDS ----
    #pragma unroll
    for (int r = 0; r < 4; ++r) {
      const int q = sl*4 + r;
      const int sw = (q & 7) << 3;
      psw[(q*32 + fc) ^ sw]      = (_Float16)p0[r];
      psw[(q*32 + fc + 16) ^ sw] = (_Float16)p1[r];
    }
    const f16x8 pa = *(const f16x8*)&psw[(fc*32 + sl*8) ^ ((fc & 7) << 3)];
    // ---- PV ----
    #pragma unroll
    for (int dc = 0; dc < 16; ++dc)
      O[dc] = __builtin_amdgcn_mfma_f32_16x16x32_f16(pa, vv[dc], O[dc], 0, 0, 0);
  }

  // ---- reduce l over the 16 fc lanes (each lane keeps its row's l) ----
  #pragma unroll
  for (int off = 1; off < 16; off <<= 1) {
    #pragma unroll
    for (int r = 0; r < 4; ++r) l_[r] += __shfl_xor(l_[r], off, 16);
  }

  // ---- in-block merge: waves 2,3 -> LDS; 0,1 add; 1 -> LDS; 0 final ----
  __syncthreads();
  if (w >= 2) {
    float* ob = &Obuf[w - 2][0];
    #pragma unroll
    for (int dc = 0; dc < 16; ++dc)
      #pragma unroll
      for (int r = 0; r < 4; ++r)
        ob[(sl*4 + r)*260 + dc*16 + fc] = O[dc][r];
    if (fc == 0) {
      #pragma unroll
      for (int r = 0; r < 4; ++r) lbuf[w - 2][sl*4 + r] = l_[r];
    }
  }
  __syncthreads();
  if (w < 2) {
    const float* ob = &Obuf[w][0];
    #pragma unroll
    for (int dc = 0; dc < 16; ++dc)
      #pragma unroll
      for (int r = 0; r < 4; ++r)
        O[dc][r] += ob[(sl*4 + r)*260 + dc*16 + fc];
    #pragma unroll
    for (int r = 0; r < 4; ++r) l_[r] += lbuf[w][sl*4 + r];
  }
  __syncthreads();
  if (w == 1) {
    float* ob = &Obuf[0][0];
    #pragma unroll
    for (int dc = 0; dc < 16; ++dc)
      #pragma unroll
      for (int r = 0; r < 4; ++r)
        ob[(sl*4 + r)*260 + dc*16 + fc] = O[dc][r];
    if (fc == 0) {
      #pragma unroll
      for (int r = 0; r < 4; ++r) lbuf[0][sl*4 + r] = l_[r];
    }
  }
  __syncthreads();
  if (w == 0) {
    const float* ob = &Obuf[0][0];
    #pragma unroll
    for (int dc = 0; dc < 16; ++dc)
      #pragma unroll
      for (int r = 0; r < 4; ++r)
        O[dc][r] += ob[(sl*4 + r)*260 + dc*16 + fc];
    #pragma unroll
    for (int r = 0; r < 4; ++r) l_[r] += lbuf[0][sl*4 + r];

    #pragma unroll
    for (int r = 0; r < 4; ++r) {
      const int row = r0 + sl*4 + r;
      float* po = outp + (size_t)(b*NT + row)*256;
      if (row < len) {
        const float inv = 1.f / l_[r];
        #pragma unroll
        for (int dc = 0; dc < 16; ++dc)
          po[dc*16 + fc] = O[dc][r] * inv;
      } else {
        #pragma unroll
        for (int dc = 0; dc < 16; ++dc)
          po[dc*16 + fc] = vmean[b*256 + dc*16 + fc];
      }
    }
  }
}

// ---------------------------------------------------------------------------
extern "C" void kernel_launch(void* const* d_in, const int* in_sizes, int n_in,
                              void* d_out, int out_size, void* d_ws, size_t ws_size,
                              hipStream_t stream) {
  const float* query = (const float*)d_in[0];
  const float* value = (const float*)d_in[1];
  const float* aux   = (const float*)d_in[2];
  const int*   ilen  = (const int*)  d_in[3];
  const float* Wql = (const float*)d_in[4];
  const float* bql = (const float*)d_in[5];
  const float* Wq  = (const float*)d_in[6];
  const float* bq  = (const float*)d_in[7];
  const float* aq  = (const float*)d_in[8];
  const float* gq  = (const float*)d_in[9];
  const float* btq = (const float*)d_in[10];
  const float* Wk  = (const float*)d_in[11];
  const float* bk  = (const float*)d_in[12];
  const float* ak  = (const float*)d_in[13];
  const float* gk  = (const float*)d_in[14];
  const float* btk = (const float*)d_in[15];
  const float* Wv  = (const float*)d_in[16];
  const float* bv  = (const float*)d_in[17];
  const float* av  = (const float*)d_in[18];
  const float* gv  = (const float*)d_in[19];
  const float* btv = (const float*)d_in[20];
  const float* Ws  = (const float*)d_in[21];
  const float* bs  = (const float*)d_in[22];
  const float* Wt  = (const float*)d_in[23];
  const float* bt  = (const float*)d_in[24];

  float* wsf = (float*)d_ws;
  _Float16* qbuf = (_Float16*)(wsf);                 // 8 MB
  _Float16* kbuf = (_Float16*)(wsf + 2097152);       // 8 MB
  _Float16* vln  = (_Float16*)(wsf + 4194304);       // 8 MB
  _Float16* Vt   = (_Float16*)(wsf + 6291456);       // 8 MB
  _Float16* WT   = (_Float16*)(wsf + 8388608);       // 5 x 128 KB f16
  float* biasq = wsf + 8552448;
  float* biask = biasq + 2048;
  float* biasv = biask + 2048;
  float* vmean = biasv + 2048;

  _Float16* WsT = WT + 3*65536;
  _Float16* WtT = WT + 4*65536;

  prep2<<<dim3(88), dim3(256), 0, stream>>>(
      Wql, bql, Wq, bq, Wk, bk, Wv, bv, Ws, Wt, aux,
      WT, biasq, biask, biasv, vmean);

  gemm_all<<<dim3(3072), dim3(64), 0, stream>>>(
      query, value, WT, biasq, biask, biasv,
      aq, ak, av, gq, gk, gv, btq, btk, btv,
      qbuf, kbuf, vln);

  gemm_m1<<<dim3(1024), dim3(64), 0, stream>>>(
      vln, WsT, WtT, bs, bt, Vt, vmean);

  attn<<<dim3(1024), dim3(256), 0, stream>>>(
      qbuf, kbuf, Vt, ilen, vmean, (float*)d_out);
}

// Round 5
// 289.330 us; speedup vs baseline: 1.5575x; 1.5575x over previous
//
#include <hip/hip_runtime.h>
#include <math.h>

#define NB 8
#define NT 2048
#define ND 256
#define NR (NB*NT)   // 16384 rows

typedef _Float16 f16x8 __attribute__((ext_vector_type(8)));
typedef float f32x4 __attribute__((ext_vector_type(4)));

// log2(e)/16 : folds 1/sqrt(256) and exp->exp2 into q
#define QSCALE 0.09016844005556021f
// fixed softmax max (log2 domain). |s| <= 23 hard bound (LN norms = 16).
#define MFIX 8.0f

__device__ __forceinline__ float sigm_(float x) { return 1.0f / (1.0f + __expf(-x)); }
__device__ __forceinline__ float tanh_(float x) { return 1.0f - 2.0f / (__expf(2.0f*x) + 1.0f); }

// ===========================================================================
// Fragment layouts (all f16, lane = sl*16+fc, fc=lane&15, sl=lane>>4):
//  AFRAG  (qf/kf/vlnf): frag (g,c): elem e -> X[g*16 + fc][c*32 + sl*8 + e]
//         offset f16:  (g*8 + c)*512 + lane*8
//  VFRAG  (vf):        frag (b,tl,dc):     V[d=dc*16+fc][tok=tl*32+sl*8+e]
//         offset f16:  ((b*64+tl)*16 + dc)*512 + lane*8
//  WFRAG  (WTf):       frag (z,nb,c):      W_z[k=c*32+sl*8+e][n=nb*16+fc]
//         offset f16:  ((z*16+nb)*8 + c)*512 + lane*8
// Every frag = 64 lanes x 16B = 1KB contiguous -> fully coalesced loads.
// ===========================================================================

// ---------------------------------------------------------------------------
// prep2 (88 blocks x 256):
//  bid 0..15 : WcqT = f16((Wql@Wq_top)^T) into WFRAG z=0  (64x64 tiles)
//  bid 16..79: WFRAG z=1..4 from {Wk,Wv,Ws,Wt} top 256 rows (transpose)
//  bid 80..87: per-batch fused biases + vmean zero
// ---------------------------------------------------------------------------
__global__ __launch_bounds__(256) void prep2(
    const float* __restrict__ Wql, const float* __restrict__ bql,
    const float* __restrict__ Wq,  const float* __restrict__ bq,
    const float* __restrict__ Wk,  const float* __restrict__ bk,
    const float* __restrict__ Wv,  const float* __restrict__ bv,
    const float* __restrict__ Ws,  const float* __restrict__ Wt,
    const float* __restrict__ aux, _Float16* __restrict__ WTf,
    float* __restrict__ biasq, float* __restrict__ biask,
    float* __restrict__ biasv, float* __restrict__ vmean)
{
  __shared__ float LA[64*68];
  __shared__ float LB[64*68];
  const int bid = blockIdx.x;
  const int tid = threadIdx.x;

  if (bid < 16) {
    // WcqT tile: acc[i][j] = Wcq[k0+tk*4+i][n0+tn*4+j]
    const int k0 = (bid & 3) * 64, n0 = (bid >> 2) * 64;
    const int c4 = tid & 15, rr = tid >> 4;
    const int tn = tid & 15, tk = tid >> 4;
    float acc[4][4];
    #pragma unroll
    for (int i = 0; i < 4; ++i)
      #pragma unroll
      for (int j = 0; j < 4; ++j) acc[i][j] = 0.f;

    for (int mc = 0; mc < 4; ++mc) {
      const int m0 = mc * 64;
      #pragma unroll
      for (int i = 0; i < 4; ++i) {
        const int row = rr + 16*i;
        *(float4*)(LA + row*68 + c4*4) =
            *(const float4*)(Wql + (size_t)(k0 + row)*256 + m0 + c4*4);
        *(float4*)(LB + row*68 + c4*4) =
            *(const float4*)(Wq + (size_t)(m0 + row)*256 + n0 + c4*4);
      }
      __syncthreads();
      for (int m = 0; m < 64; ++m) {
        const float4 b4 = *(const float4*)(LB + m*68 + tn*4);
        #pragma unroll
        for (int i = 0; i < 4; ++i) {
          const float a = LA[(tk*4 + i)*68 + m];
          acc[i][0] = fmaf(a, b4.x, acc[i][0]);
          acc[i][1] = fmaf(a, b4.y, acc[i][1]);
          acc[i][2] = fmaf(a, b4.z, acc[i][2]);
          acc[i][3] = fmaf(a, b4.w, acc[i][3]);
        }
      }
      __syncthreads();
    }
    // scatter into WFRAG z=0
    #pragma unroll
    for (int i = 0; i < 4; ++i) {
      const int k = k0 + tk*4 + i;
      const int c = k >> 5, sl = (k >> 3) & 3, e = k & 7;
      #pragma unroll
      for (int j = 0; j < 4; ++j) {
        const int n = n0 + tn*4 + j;
        const int nb = n >> 4, fcd = n & 15;
        WTf[(size_t)(nb*8 + c)*512 + (sl*16 + fcd)*8 + e] = (_Float16)acc[i][j];
      }
    }
  } else if (bid < 80) {
    // transpose W_z top half into WFRAG z=zz+1
    const int zz = (bid - 16) >> 4;
    const int tile = (bid - 16) & 15;
    const int k0 = (tile & 3)*64, n0 = (tile >> 2)*64;
    const float* src = (zz==0) ? Wk : (zz==1) ? Wv : (zz==2) ? Ws : Wt;
    _Float16* dst = WTf + (size_t)(zz + 1)*65536;
    const int c4 = tid & 15, rr = tid >> 4;
    #pragma unroll
    for (int i = 0; i < 4; ++i) {
      const int row = rr + 16*i;
      *(float4*)(LA + row*68 + c4*4) =
          *(const float4*)(src + (size_t)(k0 + row)*256 + n0 + c4*4);
    }
    __syncthreads();
    #pragma unroll
    for (int rep = 0; rep < 2; ++rep) {
      const int q = tid + 256*rep;           // 0..511
      const int ncol = q & 63, kc = q >> 6;  // kc 0..7
      const int kg = k0 + kc*8;
      const int c = kg >> 5, sl = (kg >> 3) & 3;
      const int n = n0 + ncol;
      const int nb = n >> 4, fcd = n & 15;
      f16x8 v;
      #pragma unroll
      for (int e = 0; e < 8; ++e) v[e] = (_Float16)LA[(kc*8 + e)*68 + ncol];
      *(f16x8*)(dst + (size_t)(nb*8 + c)*512 + (sl*16 + fcd)*8) = v;
    }
  } else {
    // biases + vmean zero
    const int b = bid - 80;
    const int j = tid;
    float accq = bq[j], acck = bk[j], accv = bv[j];
    #pragma unroll 4
    for (int n = 0; n < 256; ++n)
      accq = fmaf(bql[n], Wq[n*256 + j], accq);
    #pragma unroll 4
    for (int d = 0; d < 256; ++d) {
      const float a = aux[b*256 + d];
      accq = fmaf(a, Wq[(256 + d)*256 + j], accq);
      acck = fmaf(a, Wk[(256 + d)*256 + j], acck);
      accv = fmaf(a, Wv[(256 + d)*256 + j], accv);
    }
    biasq[b*256 + j] = accq;
    biask[b*256 + j] = acck;
    biasv[b*256 + j] = accv;
    vmean[b*256 + j] = 0.f;
  }
}

// ---------------------------------------------------------------------------
// gemm_all: 3 LN streams in one launch (z = bid>>10):
//  z0: q = LN(PReLU(query@Wcq + biasq)) * QSCALE -> qf (AFRAG)
//  z1: k = LN(PReLU(value@Wk  + biask))          -> kf (AFRAG)
//  z2: v = LN(PReLU(value@Wv  + biasv))          -> vlnf (AFRAG)
// 1 wave/block, 16 rows x 256 cols. A staged via LDS (coalesced); WT frags
// coalesced; output bounced through LDS into AFRAG (coalesced).
// ---------------------------------------------------------------------------
__global__ __launch_bounds__(64) void gemm_all(
    const float* __restrict__ query, const float* __restrict__ value,
    const _Float16* __restrict__ WTf,
    const float* __restrict__ biasq, const float* __restrict__ biask,
    const float* __restrict__ biasv,
    const float* __restrict__ aq, const float* __restrict__ ak,
    const float* __restrict__ av,
    const float* __restrict__ gq, const float* __restrict__ gk,
    const float* __restrict__ gv,
    const float* __restrict__ btq, const float* __restrict__ btk,
    const float* __restrict__ btv,
    _Float16* __restrict__ qf, _Float16* __restrict__ kf,
    _Float16* __restrict__ vlnf)
{
  __shared__ char smem[16*260*4];          // fp32 A-stage, reused as f16 out-bounce
  float* LAs = (float*)smem;               // [16][260]
  _Float16* Lt = (_Float16*)smem;          // [16][264]

  const int bid = blockIdx.x;
  const int z = bid >> 10;
  const int idx = bid & 1023;
  const int lane = threadIdx.x;
  const int fc = lane & 15, sl = lane >> 4;
  const int r0 = idx * 16;
  const int b = idx >> 7;

  const float* in = (z == 0) ? query : value;
  const float* bias = (z == 0) ? biasq : (z == 1) ? biask : biasv;
  const float* alp  = (z == 0) ? aq : (z == 1) ? ak : av;
  const float* g    = (z == 0) ? gq : (z == 1) ? gk : gv;
  const float* beta = (z == 0) ? btq : (z == 1) ? btk : btv;
  _Float16* outf = (z == 0) ? qf : (z == 1) ? kf : vlnf;
  const float scale = (z == 0) ? QSCALE : 1.0f;

  // stage 16 rows of A, fully coalesced (1KB per instr)
  #pragma unroll
  for (int i = 0; i < 16; ++i)
    *(float4*)(LAs + i*260 + lane*4) =
        *(const float4*)(in + (size_t)(r0 + i)*256 + lane*4);
  __syncthreads();

  // A-frags from LDS (+ f32->f16)
  f16x8 a[8];
  #pragma unroll
  for (int c = 0; c < 8; ++c) {
    const float* src = LAs + fc*260 + c*32 + sl*8;
    const float4 x0 = *(const float4*)(src);
    const float4 x1 = *(const float4*)(src + 4);
    f16x8 t;
    t[0]=(_Float16)x0.x; t[1]=(_Float16)x0.y; t[2]=(_Float16)x0.z; t[3]=(_Float16)x0.w;
    t[4]=(_Float16)x1.x; t[5]=(_Float16)x1.y; t[6]=(_Float16)x1.z; t[7]=(_Float16)x1.w;
    a[c] = t;
  }

  f32x4 acc[16];
  #pragma unroll
  for (int n = 0; n < 16; ++n) acc[n] = (f32x4)(0.f);

  const _Float16* wz = WTf + (size_t)z * 65536;
  #pragma unroll
  for (int c = 0; c < 8; ++c) {
    #pragma unroll
    for (int n = 0; n < 16; ++n) {
      const f16x8 wf = *(const f16x8*)(wz + (size_t)(n*8 + c)*512 + lane*8);
      acc[n] = __builtin_amdgcn_mfma_f32_16x16x32_f16(a[c], wf, acc[n], 0, 0, 0);
    }
  }

  // epilogue: bias + PReLU + LN
  const float alpha = alp[0];
  float s_[4] = {0.f,0.f,0.f,0.f}, ss[4] = {0.f,0.f,0.f,0.f};
  #pragma unroll
  for (int n = 0; n < 16; ++n) {
    const float bb = bias[b*256 + n*16 + fc];
    #pragma unroll
    for (int r = 0; r < 4; ++r) {
      float x = acc[n][r] + bb;
      x = (x >= 0.f) ? x : alpha*x;
      acc[n][r] = x;
      s_[r] += x; ss[r] += x*x;
    }
  }
  #pragma unroll
  for (int off = 1; off < 16; off <<= 1) {
    #pragma unroll
    for (int r = 0; r < 4; ++r) {
      s_[r] += __shfl_xor(s_[r], off, 16);
      ss[r] += __shfl_xor(ss[r], off, 16);
    }
  }
  float mean[4], rstd[4];
  #pragma unroll
  for (int r = 0; r < 4; ++r) {
    mean[r] = s_[r] * (1.f/256.f);
    const float var = ss[r] * (1.f/256.f) - mean[r]*mean[r];
    rstd[r] = rsqrtf(var + 1e-5f);
  }
  __syncthreads();   // LAs reads done before Lt overwrite
  #pragma unroll
  for (int n = 0; n < 16; ++n) {
    const int col = n*16 + fc;
    const float gg = g[col], be = beta[col];
    #pragma unroll
    for (int r = 0; r < 4; ++r) {
      const float o = ((acc[n][r] - mean[r])*rstd[r]*gg + be) * scale;
      Lt[(sl*4 + r)*264 + col] = (_Float16)o;
    }
  }
  __syncthreads();
  // AFRAG out, coalesced
  _Float16* ob = outf + (size_t)idx * 4096;     // g = idx, 8*512
  #pragma unroll
  for (int c = 0; c < 8; ++c) {
    const f16x8 v = *(const f16x8*)(Lt + fc*264 + c*32 + sl*8);
    *(f16x8*)(ob + c*512 + lane*8) = v;
  }
}

// ---------------------------------------------------------------------------
// gemm_m1: vgate = sigmoid(vln@Ws+bs)*tanh(vln@Wt+bt) -> vf (VFRAG) + vmean.
// 256 blocks x 4 waves; block = 64 tokens = 2 V-tiles; LDS transpose.
// ---------------------------------------------------------------------------
__global__ __launch_bounds__(256) void gemm_m1(
    const _Float16* __restrict__ vlnf, const _Float16* __restrict__ WTf,
    const float* __restrict__ bs, const float* __restrict__ bt,
    _Float16* __restrict__ vf, float* __restrict__ vmean)
{
  __shared__ _Float16 Lv[256*72];
  const int w = threadIdx.x >> 6, lane = threadIdx.x & 63;
  const int fc = lane & 15, sl = lane >> 4;
  const int blk = blockIdx.x;
  const int b = blk >> 5, ch = blk & 31;
  const int g = blk*4 + w;                 // global 16-token group

  f16x8 a[8];
  const _Float16* ap = vlnf + (size_t)g*4096 + lane*8;
  #pragma unroll
  for (int c = 0; c < 8; ++c) a[c] = *(const f16x8*)(ap + c*512);

  f32x4 aS[16], aT[16];
  #pragma unroll
  for (int n = 0; n < 16; ++n) { aS[n] = (f32x4)(0.f); aT[n] = (f32x4)(0.f); }

  const _Float16* wsz = WTf + (size_t)3*65536;
  const _Float16* wtz = WTf + (size_t)4*65536;
  #pragma unroll
  for (int c = 0; c < 8; ++c) {
    #pragma unroll
    for (int n = 0; n < 16; ++n) {
      const f16x8 b1 = *(const f16x8*)(wsz + (size_t)(n*8 + c)*512 + lane*8);
      const f16x8 b2 = *(const f16x8*)(wtz + (size_t)(n*8 + c)*512 + lane*8);
      aS[n] = __builtin_amdgcn_mfma_f32_16x16x32_f16(a[c], b1, aS[n], 0, 0, 0);
      aT[n] = __builtin_amdgcn_mfma_f32_16x16x32_f16(a[c], b2, aT[n], 0, 0, 0);
    }
  }

  #pragma unroll
  for (int n = 0; n < 16; ++n) {
    const int col = n*16 + fc;
    const float b1 = bs[col], b2 = bt[col];
    float s = 0.f;
    #pragma unroll
    for (int r = 0; r < 4; ++r) {
      const float v = sigm_(aS[n][r] + b1) * tanh_(aT[n][r] + b2);
      Lv[col*72 + (w*16 + sl*4 + r)] = (_Float16)v;
      s += v;
    }
    s += __shfl_xor(s, 16, 64);
    s += __shfl_xor(s, 32, 64);
    if (sl == 0) atomicAdd(vmean + b*256 + col, s * (1.f/2048.f));
  }
  __syncthreads();
  // VFRAG out: 32 frags (h,dc), wave w writes 8, coalesced
  #pragma unroll
  for (int q = 0; q < 8; ++q) {
    const int fid = w*8 + q;
    const int h = fid >> 4, dc = fid & 15;
    const f16x8 vo = *(const f16x8*)(Lv + (dc*16 + fc)*72 + h*32 + sl*8);
    *(f16x8*)(vf + (size_t)((b*64 + ch*2 + h)*16 + dc)*512 + lane*8) = vo;
  }
}

// ---------------------------------------------------------------------------
// attn: flash attention, f16 MFMA, fixed-max softmax (log2 domain).
// 512 blocks x 4 waves. b = bid&7 (XCD pin). u = bid>>3:
//   j = u<32 ? u : 63-u  (64-row unit, balanced pairing), half = u>=32.
// All 4 waves iterate the SAME col-tile range (L1 sharing); each wave owns
// 16 q-rows. half0 -> d_out (unnorm), half1 -> pO; l -> pl; merge kernel.
// All q/k/v loads are coalesced 1KB frag loads.
// ---------------------------------------------------------------------------
__global__ __launch_bounds__(256, 2) void attn(
    const _Float16* __restrict__ qf, const _Float16* __restrict__ kf,
    const _Float16* __restrict__ vf, const int* __restrict__ ilen,
    float* __restrict__ pl, float* __restrict__ pO, float* __restrict__ outp)
{
  __shared__ _Float16 Ps[4][512];
  const int bid = blockIdx.x;
  const int b = bid & 7;
  const int u = bid >> 3;
  const int j = (u < 32) ? u : 63 - u;
  const int half = (u < 32) ? 0 : 1;
  const int r0 = j << 6;
  const int len = ilen[b];
  if (r0 >= len) return;                   // merge emits vmean for pad rows

  const int w = threadIdx.x >> 6, lane = threadIdx.x & 63;
  const int fc = lane & 15, sl = lane >> 4;
  const int nt = (min(r0 + 64, len) + 31) >> 5;
  const int nh = (nt + 1) >> 1;
  const int tb = half ? nh : 0, te = half ? nt : nh;

  const int rw = r0 + w*16;                // this wave's rows
  const int unit = b*128 + (rw >> 4);

  f16x8 aq_[8];
  {
    const _Float16* qp = qf + (size_t)unit*4096 + lane*8;
    #pragma unroll
    for (int c = 0; c < 8; ++c) aq_[c] = *(const f16x8*)(qp + c*512);
  }

  f32x4 O[16];
  #pragma unroll
  for (int dc = 0; dc < 16; ++dc) O[dc] = (f32x4)(0.f);
  float l_[4] = {0.f, 0.f, 0.f, 0.f};

  const _Float16* kfb = kf + (size_t)b * 524288;
  const _Float16* vfb = vf + (size_t)b * 524288;
  _Float16* psw = &Ps[w][0];

  for (int t = tb; t < te; ++t) {
    // ---- K frags: 16 coalesced 1KB loads ----
    f16x8 kk[16];
    const _Float16* kp = kfb + (size_t)(2*t)*4096 + lane*8;
    #pragma unroll
    for (int c = 0; c < 8; ++c) {
      kk[c]     = *(const f16x8*)(kp + c*512);
      kk[8 + c] = *(const f16x8*)(kp + 4096 + c*512);
    }
    // ---- QK^T: 4 independent MFMA chains ----
    f32x4 S0a = (f32x4)(0.f), S0b = (f32x4)(0.f);
    f32x4 S1a = (f32x4)(0.f), S1b = (f32x4)(0.f);
    #pragma unroll
    for (int c = 0; c < 4; ++c) {
      S0a = __builtin_amdgcn_mfma_f32_16x16x32_f16(aq_[c],   kk[c],    S0a, 0, 0, 0);
      S1a = __builtin_amdgcn_mfma_f32_16x16x32_f16(aq_[c],   kk[8+c],  S1a, 0, 0, 0);
      S0b = __builtin_amdgcn_mfma_f32_16x16x32_f16(aq_[4+c], kk[4+c],  S0b, 0, 0, 0);
      S1b = __builtin_amdgcn_mfma_f32_16x16x32_f16(aq_[4+c], kk[12+c], S1b, 0, 0, 0);
    }
    // ---- V frags: 16 coalesced 1KB loads (overlap softmax) ----
    f16x8 vv[16];
    const _Float16* vp = vfb + (size_t)t*8192 + lane*8;
    #pragma unroll
    for (int dc = 0; dc < 16; ++dc)
      vv[dc] = *(const f16x8*)(vp + dc*512);

    // ---- mask + fixed-max exp ----
    const int C0 = t*32 + fc, C1 = C0 + 16;
    const int Rb = rw + sl*4;
    float p0[4], p1[4];
    #pragma unroll
    for (int r = 0; r < 4; ++r) {
      const int R = Rb + r;
      const bool okR = (R < len);
      const float x0 = S0a[r] + S0b[r];
      const float x1 = S1a[r] + S1b[r];
      p0[r] = (okR && (C0 <= R) && (x0 != 0.f)) ? exp2f(x0 - MFIX) : 0.f;
      p1[r] = (okR && (C1 <= R) && (x1 != 0.f)) ? exp2f(x1 - MFIX) : 0.f;
      l_[r] += p0[r] + p1[r];
    }
    // ---- P: C-layout -> f16 A-frag via swizzled per-wave LDS ----
    #pragma unroll
    for (int r = 0; r < 4; ++r) {
      const int q = sl*4 + r;
      const int sw = (q & 7) << 3;
      psw[(q*32 + fc) ^ sw]      = (_Float16)p0[r];
      psw[(q*32 + fc + 16) ^ sw] = (_Float16)p1[r];
    }
    const f16x8 pa = *(const f16x8*)&psw[(fc*32 + sl*8) ^ ((fc & 7) << 3)];
    // ---- PV: 16 independent accum chains ----
    #pragma unroll
    for (int dc = 0; dc < 16; ++dc)
      O[dc] = __builtin_amdgcn_mfma_f32_16x16x32_f16(pa, vv[dc], O[dc], 0, 0, 0);
  }

  // ---- reduce l over fc lanes ----
  #pragma unroll
  for (int off = 1; off < 16; off <<= 1) {
    #pragma unroll
    for (int r = 0; r < 4; ++r) l_[r] += __shfl_xor(l_[r], off, 16);
  }
  if (fc == 0) {
    #pragma unroll
    for (int r = 0; r < 4; ++r)
      pl[half*16384 + unit*16 + sl*4 + r] = l_[r];
  }
  // ---- write unnormalized O ----
  float* po = (half == 0) ? (outp + (size_t)(b*NT + rw)*ND)
                          : (pO + (size_t)unit*4096);
  #pragma unroll
  for (int dc = 0; dc < 16; ++dc) {
    #pragma unroll
    for (int r = 0; r < 4; ++r)
      po[(size_t)(sl*4 + r)*256 + dc*16 + fc] = O[dc][r];
  }
}

// ---------------------------------------------------------------------------
// attn_merge: out = (O_half0[d_out] + O_half1[pO]) / (l0+l1); pad -> vmean.
// 1024 blocks (one per 16-row unit) x 256 thr.
// ---------------------------------------------------------------------------
__global__ __launch_bounds__(256) void attn_merge(
    const float* __restrict__ pl, const float* __restrict__ pO,
    const float* __restrict__ vmean, const int* __restrict__ ilen,
    float* __restrict__ outp)
{
  const int unit = blockIdx.x;
  const int b = unit >> 7, rg = unit & 127;
  const int r0 = rg << 4;
  const int len = ilen[b];
  const int t = threadIdx.x;
  const int row = t >> 4, d0 = (t & 15) << 4;
  const int rowg = r0 + row;
  float4* o4 = (float4*)(outp + (size_t)(b*NT + rowg)*ND + d0);
  if (rowg >= len) {
    const float4* vm4 = (const float4*)(vmean + b*ND + d0);
    #pragma unroll
    for (int ii = 0; ii < 4; ++ii) o4[ii] = vm4[ii];
    return;
  }
  const float l0 = pl[unit*16 + row];
  const float l1 = pl[16384 + unit*16 + row];
  const float inv = 1.f / (l0 + l1);
  const float4* b4 = (const float4*)(pO + (size_t)unit*4096 + row*256 + d0);
  #pragma unroll
  for (int ii = 0; ii < 4; ++ii) {
    float4 a = o4[ii];
    const float4 bb = b4[ii];
    a.x = (a.x + bb.x) * inv;
    a.y = (a.y + bb.y) * inv;
    a.z = (a.z + bb.z) * inv;
    a.w = (a.w + bb.w) * inv;
    o4[ii] = a;
  }
}

// ---------------------------------------------------------------------------
extern "C" void kernel_launch(void* const* d_in, const int* in_sizes, int n_in,
                              void* d_out, int out_size, void* d_ws, size_t ws_size,
                              hipStream_t stream) {
  const float* query = (const float*)d_in[0];
  const float* value = (const float*)d_in[1];
  const float* aux   = (const float*)d_in[2];
  const int*   ilen  = (const int*)  d_in[3];
  const float* Wql = (const float*)d_in[4];
  const float* bql = (const float*)d_in[5];
  const float* Wq  = (const float*)d_in[6];
  const float* bq  = (const float*)d_in[7];
  const float* aq  = (const float*)d_in[8];
  const float* gq  = (const float*)d_in[9];
  const float* btq = (const float*)d_in[10];
  const float* Wk  = (const float*)d_in[11];
  const float* bk  = (const float*)d_in[12];
  const float* ak  = (const float*)d_in[13];
  const float* gk  = (const float*)d_in[14];
  const float* btk = (const float*)d_in[15];
  const float* Wv  = (const float*)d_in[16];
  const float* bv  = (const float*)d_in[17];
  const float* av  = (const float*)d_in[18];
  const float* gv  = (const float*)d_in[19];
  const float* btv = (const float*)d_in[20];
  const float* Ws  = (const float*)d_in[21];
  const float* bs  = (const float*)d_in[22];
  const float* Wt  = (const float*)d_in[23];
  const float* bt  = (const float*)d_in[24];

  float* wsf = (float*)d_ws;
  _Float16* qf   = (_Float16*)(wsf);                 // 4,194,304 f16 (8 MB)
  _Float16* kf   = (_Float16*)(wsf + 2097152);
  _Float16* vlnf = (_Float16*)(wsf + 4194304);
  _Float16* vf   = (_Float16*)(wsf + 6291456);
  _Float16* WTf  = (_Float16*)(wsf + 8388608);       // 327,680 f16 (640 KB)
  float* biasq = wsf + 8552448;
  float* biask = biasq + 2048;
  float* biasv = biask + 2048;
  float* vmean = biasv + 2048;
  float* pl    = vmean + 2048;                       // 32768 floats
  float* pO    = wsf + 8593408;                      // 4,194,304 floats (16 MB)

  prep2<<<dim3(88), dim3(256), 0, stream>>>(
      Wql, bql, Wq, bq, Wk, bk, Wv, bv, Ws, Wt, aux,
      WTf, biasq, biask, biasv, vmean);

  gemm_all<<<dim3(3072), dim3(64), 0, stream>>>(
      query, value, WTf, biasq, biask, biasv,
      aq, ak, av, gq, gk, gv, btq, btk, btv,
      qf, kf, vlnf);

  gemm_m1<<<dim3(256), dim3(256), 0, stream>>>(
      vlnf, WTf, bs, bt, vf, vmean);

  attn<<<dim3(512), dim3(256), 0, stream>>>(
      qf, kf, vf, ilen, pl, pO, (float*)d_out);

  attn_merge<<<dim3(1024), dim3(256), 0, stream>>>(
      pl, pO, vmean, ilen, (float*)d_out);
}

// Round 7
// 227.698 us; speedup vs baseline: 1.9791x; 1.2707x over previous
//
#include <hip/hip_runtime.h>
#include <math.h>

#define NB 8
#define NT 2048
#define ND 256
#define NR (NB*NT)   // 16384 rows

typedef _Float16 f16x8 __attribute__((ext_vector_type(8)));
typedef _Float16 f16x4 __attribute__((ext_vector_type(4)));
typedef float f32x4 __attribute__((ext_vector_type(4)));

// log2(e)/16 : folds 1/sqrt(256) and exp->exp2 into q
#define QSCALE 0.09016844005556021f
// fixed softmax max (log2 domain). |s| <= 23 hard bound (LN norms = 16).
#define MFIX 8.0f

__device__ __forceinline__ float sigm_(float x) { return 1.0f / (1.0f + __expf(-x)); }
__device__ __forceinline__ float tanh_(float x) { return 1.0f - 2.0f / (__expf(2.0f*x) + 1.0f); }

// ===========================================================================
// Fragment layouts (all f16, lane = sl*16+fc, fc=lane&15, sl=lane>>4):
//  AFRAG  (qf/kf): frag (g,c): elem e -> X[g*16 + fc][c*32 + sl*8 + e]
//         offset f16:  (g*8 + c)*512 + lane*8
//  VFRAG  (vf):    frag (b,tl,dc): elem e -> V[d=dc*16+fc][tok=tl*32+sl*8+e]
//         offset f16:  ((b*64+tl)*16 + dc)*512 + lane*8
//  WFRAG  (WTf):   frag (z,nb,c):  elem e -> W_z[k=c*32+sl*8+e][n=nb*16+fc]
//         offset f16:  ((z*16+nb)*8 + c)*512 + lane*8
// Every frag = 64 lanes x 16B = 1KB contiguous -> fully coalesced loads.
// ===========================================================================

// ---------------------------------------------------------------------------
// prep2 (88 blocks x 256):
//  bid 0..15 : WcqT = f16((Wql@Wq_top)^T) into WFRAG z=0  (64x64 tiles)
//  bid 16..79: WFRAG z=1..4 from {Wk,Wv,Ws,Wt} top 256 rows (transpose)
//  bid 80..87: per-batch fused biases (multi-chain ILP) + vmean zero
// ---------------------------------------------------------------------------
__global__ __launch_bounds__(256) void prep2(
    const float* __restrict__ Wql, const float* __restrict__ bql,
    const float* __restrict__ Wq,  const float* __restrict__ bq,
    const float* __restrict__ Wk,  const float* __restrict__ bk,
    const float* __restrict__ Wv,  const float* __restrict__ bv,
    const float* __restrict__ Ws,  const float* __restrict__ Wt,
    const float* __restrict__ aux, _Float16* __restrict__ WTf,
    float* __restrict__ biasq, float* __restrict__ biask,
    float* __restrict__ biasv, float* __restrict__ vmean)
{
  __shared__ float LA[64*68];
  __shared__ float LB[64*68];
  const int bid = blockIdx.x;
  const int tid = threadIdx.x;

  if (bid < 16) {
    // WcqT tile: acc[i][j] = Wcq[k0+tk*4+i][n0+tn*4+j]
    const int k0 = (bid & 3) * 64, n0 = (bid >> 2) * 64;
    const int c4 = tid & 15, rr = tid >> 4;
    const int tn = tid & 15, tk = tid >> 4;
    float acc[4][4];
    #pragma unroll
    for (int i = 0; i < 4; ++i)
      #pragma unroll
      for (int j = 0; j < 4; ++j) acc[i][j] = 0.f;

    for (int mc = 0; mc < 4; ++mc) {
      const int m0 = mc * 64;
      #pragma unroll
      for (int i = 0; i < 4; ++i) {
        const int row = rr + 16*i;
        *(float4*)(LA + row*68 + c4*4) =
            *(const float4*)(Wql + (size_t)(k0 + row)*256 + m0 + c4*4);
        *(float4*)(LB + row*68 + c4*4) =
            *(const float4*)(Wq + (size_t)(m0 + row)*256 + n0 + c4*4);
      }
      __syncthreads();
      for (int m = 0; m < 64; ++m) {
        const float4 b4 = *(const float4*)(LB + m*68 + tn*4);
        #pragma unroll
        for (int i = 0; i < 4; ++i) {
          const float a = LA[(tk*4 + i)*68 + m];
          acc[i][0] = fmaf(a, b4.x, acc[i][0]);
          acc[i][1] = fmaf(a, b4.y, acc[i][1]);
          acc[i][2] = fmaf(a, b4.z, acc[i][2]);
          acc[i][3] = fmaf(a, b4.w, acc[i][3]);
        }
      }
      __syncthreads();
    }
    // scatter into WFRAG z=0
    #pragma unroll
    for (int i = 0; i < 4; ++i) {
      const int k = k0 + tk*4 + i;
      const int c = k >> 5, sl = (k >> 3) & 3, e = k & 7;
      #pragma unroll
      for (int j = 0; j < 4; ++j) {
        const int n = n0 + tn*4 + j;
        const int nb = n >> 4, fcd = n & 15;
        WTf[(size_t)(nb*8 + c)*512 + (sl*16 + fcd)*8 + e] = (_Float16)acc[i][j];
      }
    }
  } else if (bid < 80) {
    // transpose W_z top half into WFRAG z=zz+1
    const int zz = (bid - 16) >> 4;
    const int tile = (bid - 16) & 15;
    const int k0 = (tile & 3)*64, n0 = (tile >> 2)*64;
    const float* src = (zz==0) ? Wk : (zz==1) ? Wv : (zz==2) ? Ws : Wt;
    _Float16* dst = WTf + (size_t)(zz + 1)*65536;
    const int c4 = tid & 15, rr = tid >> 4;
    #pragma unroll
    for (int i = 0; i < 4; ++i) {
      const int row = rr + 16*i;
      *(float4*)(LA + row*68 + c4*4) =
          *(const float4*)(src + (size_t)(k0 + row)*256 + n0 + c4*4);
    }
    __syncthreads();
    #pragma unroll
    for (int rep = 0; rep < 2; ++rep) {
      const int q = tid + 256*rep;           // 0..511
      const int ncol = q & 63, kc = q >> 6;  // kc 0..7
      const int kg = k0 + kc*8;
      const int c = kg >> 5, sl = (kg >> 3) & 3;
      const int n = n0 + ncol;
      const int nb = n >> 4, fcd = n & 15;
      f16x8 v;
      #pragma unroll
      for (int e = 0; e < 8; ++e) v[e] = (_Float16)LA[(kc*8 + e)*68 + ncol];
      *(f16x8*)(dst + (size_t)(nb*8 + c)*512 + (sl*16 + fcd)*8) = v;
    }
  } else {
    // biases + vmean zero (4 independent FMA chains each)
    const int b = bid - 80;
    const int j = tid;
    float q0=0.f,q1=0.f,q2=0.f,q3=0.f;
    #pragma unroll 2
    for (int n = 0; n < 256; n += 4) {
      q0 = fmaf(bql[n+0], Wq[(size_t)(n+0)*256 + j], q0);
      q1 = fmaf(bql[n+1], Wq[(size_t)(n+1)*256 + j], q1);
      q2 = fmaf(bql[n+2], Wq[(size_t)(n+2)*256 + j], q2);
      q3 = fmaf(bql[n+3], Wq[(size_t)(n+3)*256 + j], q3);
    }
    float k0=0.f,k1=0.f,v0=0.f,v1=0.f;
    #pragma unroll 2
    for (int d = 0; d < 256; d += 2) {
      const float a0 = aux[b*256 + d], a1 = aux[b*256 + d + 1];
      q0 = fmaf(a0, Wq[(size_t)(256+d)*256 + j], q0);
      k0 = fmaf(a0, Wk[(size_t)(256+d)*256 + j], k0);
      v0 = fmaf(a0, Wv[(size_t)(256+d)*256 + j], v0);
      q1 = fmaf(a1, Wq[(size_t)(257+d)*256 + j], q1);
      k1 = fmaf(a1, Wk[(size_t)(257+d)*256 + j], k1);
      v1 = fmaf(a1, Wv[(size_t)(257+d)*256 + j], v1);
    }
    biasq[b*256 + j] = bq[j] + (q0+q1) + (q2+q3);
    biask[b*256 + j] = bk[j] + k0 + k1;
    biasv[b*256 + j] = bv[j] + v0 + v1;
    vmean[b*256 + j] = 0.f;
  }
}

// ---------------------------------------------------------------------------
// gemm_fused: 768 blocks x 256 thr (4 waves); block = 64 rows; wave = 64 cols.
//  z = 2 (bid<256, dispatched first): v-stream: LN -> vln in LDS -> dual GEMM
//      (Ws,Wt) -> gate -> VFRAG vf + vmean atomics.
//  z = 0/1: q/k-stream: LN -> AFRAG qf/kf.
// A staged in LDS as f16; W frags read once per block per nb (L2).
// ---------------------------------------------------------------------------
__global__ __launch_bounds__(256, 2) void gemm_fused(
    const float* __restrict__ query, const float* __restrict__ value,
    const _Float16* __restrict__ WTf,
    const float* __restrict__ biasq, const float* __restrict__ biask,
    const float* __restrict__ biasv,
    const float* __restrict__ aq, const float* __restrict__ ak,
    const float* __restrict__ av,
    const float* __restrict__ gq, const float* __restrict__ gk,
    const float* __restrict__ gv,
    const float* __restrict__ btq, const float* __restrict__ btk,
    const float* __restrict__ btv,
    const float* __restrict__ bs, const float* __restrict__ bt,
    _Float16* __restrict__ qf, _Float16* __restrict__ kf,
    _Float16* __restrict__ vf, float* __restrict__ vmean)
{
  __shared__ _Float16 smem[18432];   // Af/Lt [64][264] (33.8KB) / Lv [256][72] (36.9KB)
  __shared__ float red[64][8];       // per-row LN partials: [row][w]=s, [row][4+w]=ss

  const int bid = blockIdx.x;
  const int z = (bid < 256) ? 2 : ((bid < 512) ? 0 : 1);
  const int idx = bid & 255;
  const int tid = threadIdx.x;
  const int w = tid >> 6;
  const int lane = tid & 63;
  const int fc = lane & 15, sl = lane >> 4;
  const int r0 = idx * 64;
  const int b = idx >> 5;

  const float* in   = (z == 0) ? query : value;
  const float* bias = (z == 0) ? biasq : (z == 1) ? biask : biasv;
  const float* alp  = (z == 0) ? aq : (z == 1) ? ak : av;
  const float* gg_  = (z == 0) ? gq : (z == 1) ? gk : gv;
  const float* bet  = (z == 0) ? btq : (z == 1) ? btk : btv;
  const float scale = (z == 0) ? QSCALE : 1.0f;

  _Float16* Af = smem;               // [64][264]

  // ---- stage A (f32 -> f16), fully coalesced ----
  #pragma unroll
  for (int i = 0; i < 16; ++i) {
    const int idx4 = i*256 + tid;
    const int row = idx4 >> 6, c4 = idx4 & 63;
    const float4 v = *(const float4*)(in + (size_t)(r0 + row)*256 + c4*4);
    f16x4 h;
    h[0] = (_Float16)v.x; h[1] = (_Float16)v.y;
    h[2] = (_Float16)v.z; h[3] = (_Float16)v.w;
    *(f16x4*)(Af + row*264 + c4*4) = h;
  }
  __syncthreads();

  // ---- phase 1 GEMM: acc[g][nbl], wave w covers cols w*64 .. w*64+63 ----
  f32x4 acc[4][4];
  #pragma unroll
  for (int g = 0; g < 4; ++g)
    #pragma unroll
    for (int nbl = 0; nbl < 4; ++nbl) acc[g][nbl] = (f32x4)(0.f);

  const _Float16* wz = WTf + (size_t)((z == 2) ? 2 : z) * 65536;
  #pragma unroll
  for (int c = 0; c < 8; ++c) {
    f16x8 ag[4];
    #pragma unroll
    for (int g = 0; g < 4; ++g)
      ag[g] = *(const f16x8*)(Af + (g*16 + fc)*264 + c*32 + sl*8);
    #pragma unroll
    for (int nbl = 0; nbl < 4; ++nbl) {
      const f16x8 wf = *(const f16x8*)(wz + (size_t)((w*4 + nbl)*8 + c)*512 + lane*8);
      #pragma unroll
      for (int g = 0; g < 4; ++g)
        acc[g][nbl] = __builtin_amdgcn_mfma_f32_16x16x32_f16(ag[g], wf, acc[g][nbl], 0, 0, 0);
    }
  }

  // ---- epilogue: bias + PReLU + cross-wave LN ----
  const float alpha = alp[0];
  float sg[4][4], ssg[4][4];
  #pragma unroll
  for (int g = 0; g < 4; ++g)
    #pragma unroll
    for (int r = 0; r < 4; ++r) { sg[g][r] = 0.f; ssg[g][r] = 0.f; }
  #pragma unroll
  for (int nbl = 0; nbl < 4; ++nbl) {
    const float bb = bias[b*256 + (w*4 + nbl)*16 + fc];
    #pragma unroll
    for (int g = 0; g < 4; ++g) {
      #pragma unroll
      for (int r = 0; r < 4; ++r) {
        float x = acc[g][nbl][r] + bb;
        x = (x >= 0.f) ? x : alpha*x;
        acc[g][nbl][r] = x;
        sg[g][r] += x; ssg[g][r] += x*x;
      }
    }
  }
  #pragma unroll
  for (int off = 1; off < 16; off <<= 1) {
    #pragma unroll
    for (int g = 0; g < 4; ++g)
      #pragma unroll
      for (int r = 0; r < 4; ++r) {
        sg[g][r]  += __shfl_xor(sg[g][r],  off, 16);
        ssg[g][r] += __shfl_xor(ssg[g][r], off, 16);
      }
  }
  if (fc == 0) {
    #pragma unroll
    for (int g = 0; g < 4; ++g)
      #pragma unroll
      for (int r = 0; r < 4; ++r) {
        red[g*16 + sl*4 + r][w]     = sg[g][r];
        red[g*16 + sl*4 + r][4 + w] = ssg[g][r];
      }
  }
  __syncthreads();   // red ready; also all Af reads complete

  float mean[4][4], rstd[4][4];
  #pragma unroll
  for (int g = 0; g < 4; ++g) {
    #pragma unroll
    for (int r = 0; r < 4; ++r) {
      const int row = g*16 + sl*4 + r;
      const float s  = (red[row][0] + red[row][1]) + (red[row][2] + red[row][3]);
      const float ss = (red[row][4] + red[row][5]) + (red[row][6] + red[row][7]);
      mean[g][r] = s * (1.f/256.f);
      const float var = ss * (1.f/256.f) - mean[g][r]*mean[g][r];
      rstd[g][r] = rsqrtf(var + 1e-5f);
    }
  }

  // ---- apply LN, write Lt (reuse Af) ----
  _Float16* Lt = Af;
  #pragma unroll
  for (int nbl = 0; nbl < 4; ++nbl) {
    const int col = (w*4 + nbl)*16 + fc;
    const float gv_ = gg_[col], be = bet[col];
    #pragma unroll
    for (int g = 0; g < 4; ++g) {
      #pragma unroll
      for (int r = 0; r < 4; ++r) {
        const float o = ((acc[g][nbl][r] - mean[g][r])*rstd[g][r]*gv_ + be) * scale;
        Lt[(g*16 + sl*4 + r)*264 + col] = (_Float16)o;
      }
    }
  }
  __syncthreads();

  if (z != 2) {
    // ---- AFRAG out: wave w writes row-group g'=w, frags c=0..7 ----
    _Float16* ob = ((z == 0) ? qf : kf) + (size_t)(idx*4 + w)*4096;
    #pragma unroll
    for (int c = 0; c < 8; ++c) {
      const f16x8 v = *(const f16x8*)(Lt + (w*16 + fc)*264 + c*32 + sl*8);
      *(f16x8*)(ob + c*512 + lane*8) = v;
    }
  } else {
    // ---- phase 2: dual GEMM (Ws, Wt) on vln from Lt ----
    f32x4 aS[4][4], aT[4][4];
    #pragma unroll
    for (int g = 0; g < 4; ++g)
      #pragma unroll
      for (int nbl = 0; nbl < 4; ++nbl) { aS[g][nbl] = (f32x4)(0.f); aT[g][nbl] = (f32x4)(0.f); }
    const _Float16* wsz = WTf + (size_t)3*65536;
    const _Float16* wtz = WTf + (size_t)4*65536;
    #pragma unroll
    for (int c = 0; c < 8; ++c) {
      f16x8 ag[4];
      #pragma unroll
      for (int g = 0; g < 4; ++g)
        ag[g] = *(const f16x8*)(Lt + (g*16 + fc)*264 + c*32 + sl*8);
      #pragma unroll
      for (int nbl = 0; nbl < 4; ++nbl) {
        const f16x8 w1 = *(const f16x8*)(wsz + (size_t)((w*4 + nbl)*8 + c)*512 + lane*8);
        const f16x8 w2 = *(const f16x8*)(wtz + (size_t)((w*4 + nbl)*8 + c)*512 + lane*8);
        #pragma unroll
        for (int g = 0; g < 4; ++g) {
          aS[g][nbl] = __builtin_amdgcn_mfma_f32_16x16x32_f16(ag[g], w1, aS[g][nbl], 0, 0, 0);
          aT[g][nbl] = __builtin_amdgcn_mfma_f32_16x16x32_f16(ag[g], w2, aT[g][nbl], 0, 0, 0);
        }
      }
    }
    // ---- gate + vmean atomics ----
    #pragma unroll
    for (int nbl = 0; nbl < 4; ++nbl) {
      const int col = (w*4 + nbl)*16 + fc;
      const float b1 = bs[col], b2 = bt[col];
      float colsum = 0.f;
      #pragma unroll
      for (int g = 0; g < 4; ++g) {
        #pragma unroll
        for (int r = 0; r < 4; ++r) {
          const float v = sigm_(aS[g][nbl][r] + b1) * tanh_(aT[g][nbl][r] + b2);
          aS[g][nbl][r] = v;
          colsum += v;
        }
      }
      colsum += __shfl_xor(colsum, 16, 64);
      colsum += __shfl_xor(colsum, 32, 64);
      if (sl == 0) atomicAdd(vmean + b*256 + col, colsum * (1.f/2048.f));
    }
    __syncthreads();   // Lt reads done before Lv overwrite
    _Float16* Lv = smem;              // [256][72]
    #pragma unroll
    for (int nbl = 0; nbl < 4; ++nbl) {
      const int col = (w*4 + nbl)*16 + fc;
      #pragma unroll
      for (int g = 0; g < 4; ++g)
        #pragma unroll
        for (int r = 0; r < 4; ++r)
          Lv[col*72 + g*16 + sl*4 + r] = (_Float16)aS[g][nbl][r];
    }
    __syncthreads();
    // ---- VFRAG out: 32 frags (tl 0..1, dc 0..15), wave w writes 8 ----
    #pragma unroll
    for (int q = 0; q < 8; ++q) {
      const int fid = w*8 + q;
      const int tl = fid >> 4, dc = fid & 15;
      const f16x8 vo = *(const f16x8*)(Lv + (dc*16 + fc)*72 + tl*32 + sl*8);
      *(f16x8*)(vf + (size_t)((b*64 + (idx & 31)*2 + tl)*16 + dc)*512 + lane*8) = vo;
    }
  }
}

// ---------------------------------------------------------------------------
// attn: flash attention, f16 MFMA, fixed-max softmax (log2 domain), NO split.
// 1024 blocks x 4 waves. b = bid&7 (XCD pin); u = 127-(bid>>3) (heavy-first).
// Block owns one 16-row unit; waves take col-tiles t = w, w+4, ...;
// in-block LDS merge; direct normalized write (pad rows -> vmean).
// ---------------------------------------------------------------------------
__global__ __launch_bounds__(256, 2) void attn(
    const _Float16* __restrict__ qf, const _Float16* __restrict__ kf,
    const _Float16* __restrict__ vf, const int* __restrict__ ilen,
    const float* __restrict__ vmean, float* __restrict__ outp)
{
  __shared__ _Float16 Ps[4][512];
  __shared__ float Obuf[2][16*260];
  __shared__ float lbuf[2][16];

  const int bid = blockIdx.x;
  const int b = bid & 7;
  const int u = 127 - (bid >> 3);          // heavy-first dispatch
  const int r0 = u << 4;
  const int len = ilen[b];
  const int w = threadIdx.x >> 6, lane = threadIdx.x & 63;
  const int fc = lane & 15, sl = lane >> 4;

  if (r0 >= len) {                          // pad-only unit -> vmean rows
    const int row = threadIdx.x >> 4;
    const int c4 = threadIdx.x & 15;
    const float4* vm4 = (const float4*)(vmean + b*ND);
    float4* o4 = (float4*)(outp + (size_t)(b*NT + r0 + row)*ND);
    #pragma unroll
    for (int ii = 0; ii < 4; ++ii) o4[c4 + 16*ii] = vm4[c4 + 16*ii];
    return;
  }

  const int nt = (min(r0 + 16, len) + 31) >> 5;
  const int unit = b*128 + u;

  f16x8 aq_[8];
  {
    const _Float16* qp = qf + (size_t)unit*4096 + lane*8;
    #pragma unroll
    for (int c = 0; c < 8; ++c) aq_[c] = *(const f16x8*)(qp + c*512);
  }

  f32x4 O[16];
  #pragma unroll
  for (int dc = 0; dc < 16; ++dc) O[dc] = (f32x4)(0.f);
  float l_[4] = {0.f, 0.f, 0.f, 0.f};

  const _Float16* kfb = kf + (size_t)b * 524288;
  const _Float16* vfb = vf + (size_t)b * 524288;
  _Float16* psw = &Ps[w][0];

  for (int t = w; t < nt; t += 4) {
    // ---- K frags: 16 coalesced 1KB loads ----
    f16x8 kk[16];
    const _Float16* kp = kfb + (size_t)(2*t)*4096 + lane*8;
    #pragma unroll
    for (int c = 0; c < 8; ++c) {
      kk[c]     = *(const f16x8*)(kp + c*512);
      kk[8 + c] = *(const f16x8*)(kp + 4096 + c*512);
    }
    // ---- QK^T: 4 independent MFMA chains ----
    f32x4 S0a = (f32x4)(0.f), S0b = (f32x4)(0.f);
    f32x4 S1a = (f32x4)(0.f), S1b = (f32x4)(0.f);
    #pragma unroll
    for (int c = 0; c < 4; ++c) {
      S0a = __builtin_amdgcn_mfma_f32_16x16x32_f16(aq_[c],   kk[c],    S0a, 0, 0, 0);
      S1a = __builtin_amdgcn_mfma_f32_16x16x32_f16(aq_[c],   kk[8+c],  S1a, 0, 0, 0);
      S0b = __builtin_amdgcn_mfma_f32_16x16x32_f16(aq_[4+c], kk[4+c],  S0b, 0, 0, 0);
      S1b = __builtin_amdgcn_mfma_f32_16x16x32_f16(aq_[4+c], kk[12+c], S1b, 0, 0, 0);
    }
    // ---- V frags: 16 coalesced 1KB loads (latency under softmax) ----
    f16x8 vv[16];
    const _Float16* vp = vfb + (size_t)t*8192 + lane*8;
    #pragma unroll
    for (int dc = 0; dc < 16; ++dc)
      vv[dc] = *(const f16x8*)(vp + dc*512);

    // ---- mask + fixed-max exp ----
    const int C0 = t*32 + fc, C1 = C0 + 16;
    const int Rb = r0 + sl*4;
    float p0[4], p1[4];
    #pragma unroll
    for (int r = 0; r < 4; ++r) {
      const int R = Rb + r;
      const bool okR = (R < len);
      const float x0 = S0a[r] + S0b[r];
      const float x1 = S1a[r] + S1b[r];
      p0[r] = (okR && (C0 <= R) && (x0 != 0.f)) ? exp2f(x0 - MFIX) : 0.f;
      p1[r] = (okR && (C1 <= R) && (x1 != 0.f)) ? exp2f(x1 - MFIX) : 0.f;
      l_[r] += p0[r] + p1[r];
    }
    // ---- P: C-layout -> f16 A-frag via swizzled per-wave LDS ----
    #pragma unroll
    for (int r = 0; r < 4; ++r) {
      const int q = sl*4 + r;
      const int sw = (q & 7) << 3;
      psw[(q*32 + fc) ^ sw]      = (_Float16)p0[r];
      psw[(q*32 + fc + 16) ^ sw] = (_Float16)p1[r];
    }
    const f16x8 pa = *(const f16x8*)&psw[(fc*32 + sl*8) ^ ((fc & 7) << 3)];
    // ---- PV: 16 independent accum chains ----
    #pragma unroll
    for (int dc = 0; dc < 16; ++dc)
      O[dc] = __builtin_amdgcn_mfma_f32_16x16x32_f16(pa, vv[dc], O[dc], 0, 0, 0);
  }

  // ---- reduce l over fc lanes ----
  #pragma unroll
  for (int off = 1; off < 16; off <<= 1) {
    #pragma unroll
    for (int r = 0; r < 4; ++r) l_[r] += __shfl_xor(l_[r], off, 16);
  }

  // ---- in-block merge: waves 2,3 -> LDS; 0,1 add; 1 -> LDS; 0 final ----
  __syncthreads();
  if (w >= 2) {
    float* ob = &Obuf[w - 2][0];
    #pragma unroll
    for (int dc = 0; dc < 16; ++dc)
      #pragma unroll
      for (int r = 0; r < 4; ++r)
        ob[(sl*4 + r)*260 + dc*16 + fc] = O[dc][r];
    if (fc == 0) {
      #pragma unroll
      for (int r = 0; r < 4; ++r) lbuf[w - 2][sl*4 + r] = l_[r];
    }
  }
  __syncthreads();
  if (w < 2) {
    const float* ob = &Obuf[w][0];
    #pragma unroll
    for (int dc = 0; dc < 16; ++dc)
      #pragma unroll
      for (int r = 0; r < 4; ++r)
        O[dc][r] += ob[(sl*4 + r)*260 + dc*16 + fc];
    #pragma unroll
    for (int r = 0; r < 4; ++r) l_[r] += lbuf[w][sl*4 + r];
  }
  __syncthreads();
  if (w == 1) {
    float* ob = &Obuf[0][0];
    #pragma unroll
    for (int dc = 0; dc < 16; ++dc)
      #pragma unroll
      for (int r = 0; r < 4; ++r)
        ob[(sl*4 + r)*260 + dc*16 + fc] = O[dc][r];
    if (fc == 0) {
      #pragma unroll
      for (int r = 0; r < 4; ++r) lbuf[0][sl*4 + r] = l_[r];
    }
  }
  __syncthreads();
  if (w == 0) {
    const float* ob = &Obuf[0][0];
    #pragma unroll
    for (int dc = 0; dc < 16; ++dc)
      #pragma unroll
      for (int r = 0; r < 4; ++r)
        O[dc][r] += ob[(sl*4 + r)*260 + dc*16 + fc];
    #pragma unroll
    for (int r = 0; r < 4; ++r) l_[r] += lbuf[0][sl*4 + r];

    #pragma unroll
    for (int r = 0; r < 4; ++r) {
      const int row = r0 + sl*4 + r;
      float* po = outp + (size_t)(b*NT + row)*256;
      if (row < len) {
        const float inv = 1.f / l_[r];
        #pragma unroll
        for (int dc = 0; dc < 16; ++dc)
          po[dc*16 + fc] = O[dc][r] * inv;
      } else {
        #pragma unroll
        for (int dc = 0; dc < 16; ++dc)
          po[dc*16 + fc] = vmean[b*256 + dc*16 + fc];
      }
    }
  }
}

// ---------------------------------------------------------------------------
extern "C" void kernel_launch(void* const* d_in, const int* in_sizes, int n_in,
                              void* d_out, int out_size, void* d_ws, size_t ws_size,
                              hipStream_t stream) {
  const float* query = (const float*)d_in[0];
  const float* value = (const float*)d_in[1];
  const float* aux   = (const float*)d_in[2];
  const int*   ilen  = (const int*)  d_in[3];
  const float* Wql = (const float*)d_in[4];
  const float* bql = (const float*)d_in[5];
  const float* Wq  = (const float*)d_in[6];
  const float* bq  = (const float*)d_in[7];
  const float* aq  = (const float*)d_in[8];
  const float* gq  = (const float*)d_in[9];
  const float* btq = (const float*)d_in[10];
  const float* Wk  = (const float*)d_in[11];
  const float* bk  = (const float*)d_in[12];
  const float* ak  = (const float*)d_in[13];
  const float* gk  = (const float*)d_in[14];
  const float* btk = (const float*)d_in[15];
  const float* Wv  = (const float*)d_in[16];
  const float* bv  = (const float*)d_in[17];
  const float* av  = (const float*)d_in[18];
  const float* gv  = (const float*)d_in[19];
  const float* btv = (const float*)d_in[20];
  const float* Ws  = (const float*)d_in[21];
  const float* bs  = (const float*)d_in[22];
  const float* Wt  = (const float*)d_in[23];
  const float* bt  = (const float*)d_in[24];

  float* wsf = (float*)d_ws;
  _Float16* qf  = (_Float16*)(wsf);                  // 4,194,304 f16 (8 MB)
  _Float16* kf  = (_Float16*)(wsf + 2097152);        // 8 MB
  _Float16* vf  = (_Float16*)(wsf + 4194304);        // 8 MB
  _Float16* WTf = (_Float16*)(wsf + 6291456);        // 327,680 f16 (640 KB)
  float* biasq = wsf + 6455296;
  float* biask = biasq + 2048;
  float* biasv = biask + 2048;
  float* vmean = biasv + 2048;

  prep2<<<dim3(88), dim3(256), 0, stream>>>(
      Wql, bql, Wq, bq, Wk, bk, Wv, bv, Ws, Wt, aux,
      WTf, biasq, biask, biasv, vmean);

  gemm_fused<<<dim3(768), dim3(256), 0, stream>>>(
      query, value, WTf, biasq, biask, biasv,
      aq, ak, av, gq, gk, gv, btq, btk, btv, bs, bt,
      qf, kf, vf, vmean);

  attn<<<dim3(1024), dim3(256), 0, stream>>>(
      qf, kf, vf, ilen, vmean, (float*)d_out);
}